// Round 1
// 1034.909 us; speedup vs baseline: 1.2926x; 1.2926x over previous
//
#include <hip/hip_runtime.h>
#include <stdint.h>

// ============================================================================
// y[m][n] = sum_k x[m][k] * W[n][k],  W = (wp>0)-(wn>0) in {-1,0,1}
// M=16384, N=4096, K=4096. bf16 MFMA (16x16x32), fp32 out.
//
// R1: replace m97-style 128^2 / 2-barrier GEMM (598 TF, MfmaUtil 25%,
// 6.7e7 LDS bank conflicts, full vmcnt(0) drain per K-step) with the
// 256^2 deep-pipelined schedule (T1 + conflict-free LDS + T3/T4 + T5):
//   - 512 thr / 8 waves (2M x 4N), per-wave 128x64 output, BK=32
//   - LDS: 4-slot ring, 32KB/slot (A 16KB + B 16KB), 128KB dynamic LDS
//   - stage tile t+3 during tile t; counted s_waitcnt vmcnt(8) at tile
//     boundaries (never 0 in main loop); epilogue drains 8->4->0
//   - slot staged during t is slot (t-1)%4 whose last reader was tile t-1
//     (barrier-separated) -> no LDS write/read race by construction
//   - LDS layout chunk-major within 16-row blocks so every fragment
//     ds_read_b128 is lane-contiguous (conflict-free); realized by
//     permuting the per-lane GLOBAL source address, LDS dest stays linear
//     (global_load_lds writes wave-base + lane*16 only)
//   - 2 phases/tile: {ds_read; 2x global_load_lds; s_barrier;
//     setprio(1) 16 MFMA setprio(0); s_barrier}  == m201 barrier density
// ============================================================================

#define M_DIM 16384
#define N_DIM 4096
#define K_DIM 4096

#define BM 256
#define BN 256
#define BK 32
#define NT (K_DIM / BK)        // 128 k-tiles
#define SLOT_U16 16384         // 32 KiB ring slot: A = 8192 u16, B = 8192 u16
#define LDS_BYTES 131072       // 4 slots * 32 KiB

typedef unsigned short u16;
typedef __attribute__((ext_vector_type(8))) __bf16 bf16x8;
typedef __attribute__((ext_vector_type(4))) float f32x4;

__device__ __forceinline__ u16 f2bf(float f) {
    unsigned u = __float_as_uint(f);
    u += 0x7FFFu + ((u >> 16) & 1u);   // round-to-nearest-even
    return (u16)(u >> 16);
}

// ---- prologue: x fp32 -> bf16 ----
__global__ void cvt_x_kernel(const float4* __restrict__ x, uint2* __restrict__ xb, int n4) {
    int i = blockIdx.x * 256 + threadIdx.x;
    if (i >= n4) return;
    float4 v = x[i];
    uint2 r;
    r.x = (unsigned)f2bf(v.x) | ((unsigned)f2bf(v.y) << 16);
    r.y = (unsigned)f2bf(v.z) | ((unsigned)f2bf(v.w) << 16);
    xb[i] = r;
}

// ---- prologue: W = (wp>0) - (wn>0) as bf16 {-1,0,1} (exact) ----
__device__ __forceinline__ unsigned enc_w(float a, float b) {
    int s = (int)(a > 0.f) - (int)(b > 0.f);
    return s == 0 ? 0u : (s > 0 ? 0x3F80u : 0xBF80u);
}

__global__ void binarize_w_kernel(const float4* __restrict__ wp, const float4* __restrict__ wn,
                                  uint2* __restrict__ wb, int n4) {
    int i = blockIdx.x * 256 + threadIdx.x;
    if (i >= n4) return;
    float4 p = wp[i];
    float4 q = wn[i];
    uint2 r;
    r.x = enc_w(p.x, q.x) | (enc_w(p.y, q.y) << 16);
    r.y = enc_w(p.z, q.z) | (enc_w(p.w, q.w) << 16);
    wb[i] = r;
}

// ---- async global -> LDS, 16B per lane ----
__device__ __forceinline__ void gload16(const u16* g, u16* l) {
    __builtin_amdgcn_global_load_lds(
        (const __attribute__((address_space(1))) void*)g,
        (__attribute__((address_space(3))) void*)l,
        16, 0, 0);
}

__launch_bounds__(512, 2)
__global__ void gemm_bin_kernel(const u16* __restrict__ A,   // [M][K] bf16 bits
                                const u16* __restrict__ B,   // [N][K] bf16 bits
                                float* __restrict__ C) {     // [M][N] fp32
    extern __shared__ __align__(16) u16 lds[];

    const int t    = threadIdx.x;
    const int lane = t & 63;
    const int wid  = t >> 6;
    const int wrow = wid >> 2;        // 0..1 : wave row (M)
    const int wcol = wid & 3;         // 0..3 : wave col (N)
    const int l15  = lane & 15;
    const int quad = lane >> 4;

    // T1: XCD-aware bijective swizzle. nwg = 16*64 = 1024, 1024 % 8 == 0.
    const int orig = blockIdx.y * 16 + blockIdx.x;
    const int wgid = (orig & 7) * 128 + (orig >> 3);
    const int bm = (wgid >> 4) * BM;  // wgid / 16
    const int bn = (wgid & 15) * BN;  // wgid % 16

    // --- staging: pre-permuted global source so LINEAR LDS == chunk-major ---
    // LDS slot layout (u16 units): off(row,c) = (row>>4)*512 + c*128 + (row&15)*8
    // thread t's 16B lands at off = t*8  ->  row = (t>>6)*16 + (t&15), c = (t>>4)&3
    const int srow = ((t >> 6) << 4) | (t & 15);   // 0..127
    const int skk  = ((t >> 4) & 3) * 8;           // k-chunk * 8
    const u16* gA0 = A + (size_t)(bm + srow) * K_DIM + skk;
    const u16* gA1 = gA0 + (size_t)128 * K_DIM;    // rows 128..255
    const u16* gB0 = B + (size_t)(bn + srow) * K_DIM + skk;
    const u16* gB1 = gB0 + (size_t)128 * K_DIM;
    const int ldst = t * 8;                        // u16 offset inside region

#define STAGE_A(S, K0) do { u16* d_ = lds + (S) * SLOT_U16 + ldst;            \
        gload16(gA0 + (K0), d_); gload16(gA1 + (K0), d_ + 4096); } while (0)
#define STAGE_B(S, K0) do { u16* d_ = lds + (S) * SLOT_U16 + 8192 + ldst;     \
        gload16(gB0 + (K0), d_); gload16(gB1 + (K0), d_ + 4096); } while (0)

    // fragment read offsets: lane-contiguous 1KB per fragment -> conflict-free
    const int aoff = (wrow * 8) * 512 + quad * 128 + l15 * 8;
    const int boff = (wcol * 4) * 512 + quad * 128 + l15 * 8;

    f32x4 acc[8][4];
#pragma unroll
    for (int i = 0; i < 8; ++i)
#pragma unroll
        for (int j = 0; j < 4; ++j) acc[i][j] = (f32x4){0.f, 0.f, 0.f, 0.f};

    // prologue: stage tiles 0,1,2 (12 loads/thread); wait oldest 4 (tile 0)
    STAGE_A(0, 0);      STAGE_B(0, 0);
    STAGE_A(1, BK);     STAGE_B(1, BK);
    STAGE_A(2, 2 * BK); STAGE_B(2, 2 * BK);
    asm volatile("s_waitcnt vmcnt(8)" ::: "memory");
    __builtin_amdgcn_s_barrier();
    __builtin_amdgcn_sched_barrier(0);

    for (int tt = 0; tt < NT; ++tt) {
        const u16* As = lds + (tt & 3) * SLOT_U16;
        const u16* Bs = As + 8192;
        const bool doStage = (tt + 3) < NT;
        const int ss = (tt + 3) & 3;              // == (tt-1)&3 : safe slot
        const int sk = (tt + 3) * BK;

        // ---- phase 1: A-half0 + all B; stage next A; MFMA m0..3 ----
        bf16x8 af[4], bf[4];
#pragma unroll
        for (int i = 0; i < 4; ++i) af[i] = *(const bf16x8*)(As + aoff + i * 512);
#pragma unroll
        for (int i = 0; i < 4; ++i) bf[i] = *(const bf16x8*)(Bs + boff + i * 512);
        if (doStage) STAGE_A(ss, sk);
        __builtin_amdgcn_s_barrier();
        __builtin_amdgcn_s_setprio(1);
#pragma unroll
        for (int mi = 0; mi < 4; ++mi)
#pragma unroll
            for (int ni = 0; ni < 4; ++ni)
                acc[mi][ni] = __builtin_amdgcn_mfma_f32_16x16x32_bf16(
                    af[mi], bf[ni], acc[mi][ni], 0, 0, 0);
        __builtin_amdgcn_s_setprio(0);
        __builtin_amdgcn_s_barrier();

        // ---- phase 2: A-half1; stage next B; MFMA m4..7 ----
#pragma unroll
        for (int i = 0; i < 4; ++i) af[i] = *(const bf16x8*)(As + aoff + (4 + i) * 512);
        if (doStage) STAGE_B(ss, sk);
        __builtin_amdgcn_s_barrier();
        __builtin_amdgcn_s_setprio(1);
#pragma unroll
        for (int mi = 0; mi < 4; ++mi)
#pragma unroll
            for (int ni = 0; ni < 4; ++ni)
                acc[4 + mi][ni] = __builtin_amdgcn_mfma_f32_16x16x32_bf16(
                    af[mi], bf[ni], acc[4 + mi][ni], 0, 0, 0);
        __builtin_amdgcn_s_setprio(0);

        // tile boundary: counted wait readies tile tt+1 (all waves wait
        // BEFORE the barrier -> cross-wave staging visible after it)
        if (tt < NT - 3)       asm volatile("s_waitcnt vmcnt(8)" ::: "memory");
        else if (tt == NT - 3) asm volatile("s_waitcnt vmcnt(4)" ::: "memory");
        else if (tt == NT - 2) asm volatile("s_waitcnt vmcnt(0)" ::: "memory");
        __builtin_amdgcn_s_barrier();
        __builtin_amdgcn_sched_barrier(0);
    }

    // epilogue: C/D layout col = lane&15, row = quad*4 + r  [m89-verified]
#pragma unroll
    for (int mi = 0; mi < 8; ++mi) {
        const int row0 = bm + wrow * 128 + mi * 16 + quad * 4;
#pragma unroll
        for (int ni = 0; ni < 4; ++ni) {
            const int col = bn + wcol * 64 + ni * 16 + l15;
#pragma unroll
            for (int r = 0; r < 4; ++r)
                C[(size_t)(row0 + r) * N_DIM + col] = acc[mi][ni][r];
        }
    }
#undef STAGE_A
#undef STAGE_B
}

extern "C" void kernel_launch(void* const* d_in, const int* in_sizes, int n_in,
                              void* d_out, int out_size, void* d_ws, size_t ws_size,
                              hipStream_t stream) {
    const float* x  = (const float*)d_in[0];   // [16384][4096]
    const float* wp = (const float*)d_in[1];   // [4096][4096]
    const float* wn = (const float*)d_in[2];
    float* out = (float*)d_out;                // [16384][4096]

    // workspace layout: [0, 128MB) x_bf16 ; [128MB, 160MB) w_bf16
    u16* xb = (u16*)d_ws;
    u16* wb = (u16*)((char*)d_ws + (size_t)M_DIM * K_DIM * sizeof(u16));

    const int nx4 = M_DIM * K_DIM / 4;   // 16,777,216 float4s
    cvt_x_kernel<<<nx4 / 256, 256, 0, stream>>>((const float4*)x, (uint2*)xb, nx4);

    const int nw4 = N_DIM * K_DIM / 4;   // 4,194,304 float4s
    binarize_w_kernel<<<nw4 / 256, 256, 0, stream>>>(
        (const float4*)wp, (const float4*)wn, (uint2*)wb, nw4);

    static int s_attr_done = 0;
    if (!s_attr_done) {
        hipFuncSetAttribute((const void*)gemm_bin_kernel,
                            hipFuncAttributeMaxDynamicSharedMemorySize, LDS_BYTES);
        s_attr_done = 1;
    }
    dim3 grid(N_DIM / BN, M_DIM / BM);   // (16, 64) -> 1024 blocks
    gemm_bin_kernel<<<grid, 512, LDS_BYTES, stream>>>(xb, wb, out);
}

// Round 2
// 1021.360 us; speedup vs baseline: 1.3098x; 1.0133x over previous
//
#include <hip/hip_runtime.h>
#include <stdint.h>

// ============================================================================
// y[m][n] = sum_k x[m][k] * W[n][k],  W = (wp>0)-(wn>0) in {-1,0,1}
// M=16384, N=4096, K=4096. bf16 MFMA (16x16x32), fp32 out.
//
// R2: drop the intra-tile barriers (they were schedule-shaping only, and
// forced all 8 waves to serialize LDS-read bursts against MFMA clusters:
// MfmaUtil stuck at 38.8% with ~800 cyc/tile of unoverlapped LDS time).
// Correctness needs only ONE boundary {counted vmcnt + s_barrier} per
// K-tile:
//   - slot tt+1's staging is drained by each wave's own vmcnt(8) before
//     the collective barrier -> visible to all after it
//   - stage target slot (tt+3)&3 == (tt-1)&3 had its last reader before
//     the PREVIOUS boundary barrier -> no write/read race at any drift
// New tile body: 12 ds_read_b128 + 4 global_load_lds issued up front,
// then 32 MFMAs (setprio-wrapped). Compiler emits counted lgkmcnt so
// MFMAs start as soon as the first fragments land; drifted waves overlap
// their read bursts with other waves' MFMA bursts.
// Carried from R1: 256^2 tile, 8 waves (2Mx4N), BK=32, 4-slot LDS ring
// (128 KB), prefetch depth 3, conflict-free chunk-major LDS (0 bank
// conflicts measured) via pre-permuted global source, XCD-bijective
// block swizzle.
// ============================================================================

#define M_DIM 16384
#define N_DIM 4096
#define K_DIM 4096

#define BM 256
#define BN 256
#define BK 32
#define NT (K_DIM / BK)        // 128 k-tiles
#define SLOT_U16 16384         // 32 KiB ring slot: A = 8192 u16, B = 8192 u16
#define LDS_BYTES 131072       // 4 slots * 32 KiB

typedef unsigned short u16;
typedef __attribute__((ext_vector_type(8))) __bf16 bf16x8;
typedef __attribute__((ext_vector_type(4))) float f32x4;

__device__ __forceinline__ u16 f2bf(float f) {
    unsigned u = __float_as_uint(f);
    u += 0x7FFFu + ((u >> 16) & 1u);   // round-to-nearest-even
    return (u16)(u >> 16);
}

// ---- prologue: x fp32 -> bf16 ----
__global__ void cvt_x_kernel(const float4* __restrict__ x, uint2* __restrict__ xb, int n4) {
    int i = blockIdx.x * 256 + threadIdx.x;
    if (i >= n4) return;
    float4 v = x[i];
    uint2 r;
    r.x = (unsigned)f2bf(v.x) | ((unsigned)f2bf(v.y) << 16);
    r.y = (unsigned)f2bf(v.z) | ((unsigned)f2bf(v.w) << 16);
    xb[i] = r;
}

// ---- prologue: W = (wp>0) - (wn>0) as bf16 {-1,0,1} (exact) ----
__device__ __forceinline__ unsigned enc_w(float a, float b) {
    int s = (int)(a > 0.f) - (int)(b > 0.f);
    return s == 0 ? 0u : (s > 0 ? 0x3F80u : 0xBF80u);
}

__global__ void binarize_w_kernel(const float4* __restrict__ wp, const float4* __restrict__ wn,
                                  uint2* __restrict__ wb, int n4) {
    int i = blockIdx.x * 256 + threadIdx.x;
    if (i >= n4) return;
    float4 p = wp[i];
    float4 q = wn[i];
    uint2 r;
    r.x = enc_w(p.x, q.x) | (enc_w(p.y, q.y) << 16);
    r.y = enc_w(p.z, q.z) | (enc_w(p.w, q.w) << 16);
    wb[i] = r;
}

// ---- async global -> LDS, 16B per lane ----
__device__ __forceinline__ void gload16(const u16* g, u16* l) {
    __builtin_amdgcn_global_load_lds(
        (const __attribute__((address_space(1))) void*)g,
        (__attribute__((address_space(3))) void*)l,
        16, 0, 0);
}

__launch_bounds__(512, 2)
__global__ void gemm_bin_kernel(const u16* __restrict__ A,   // [M][K] bf16 bits
                                const u16* __restrict__ B,   // [N][K] bf16 bits
                                float* __restrict__ C) {     // [M][N] fp32
    extern __shared__ __align__(16) u16 lds[];

    const int t    = threadIdx.x;
    const int lane = t & 63;
    const int wid  = t >> 6;
    const int wrow = wid >> 2;        // 0..1 : wave row (M)
    const int wcol = wid & 3;         // 0..3 : wave col (N)
    const int l15  = lane & 15;
    const int quad = lane >> 4;

    // T1: XCD-aware bijective swizzle. nwg = 16*64 = 1024, 1024 % 8 == 0.
    const int orig = blockIdx.y * 16 + blockIdx.x;
    const int wgid = (orig & 7) * 128 + (orig >> 3);
    const int bm = (wgid >> 4) * BM;  // wgid / 16
    const int bn = (wgid & 15) * BN;  // wgid % 16

    // --- staging: pre-permuted global source so LINEAR LDS == chunk-major ---
    // LDS slot layout (u16 units): off(row,c) = (row>>4)*512 + c*128 + (row&15)*8
    // thread t's 16B lands at off = t*8  ->  row = (t>>6)*16 + (t&15), c = (t>>4)&3
    const int srow = ((t >> 6) << 4) | (t & 15);   // 0..127
    const int skk  = ((t >> 4) & 3) * 8;           // k-chunk * 8
    const u16* gA0 = A + (size_t)(bm + srow) * K_DIM + skk;
    const u16* gA1 = gA0 + (size_t)128 * K_DIM;    // rows 128..255
    const u16* gB0 = B + (size_t)(bn + srow) * K_DIM + skk;
    const u16* gB1 = gB0 + (size_t)128 * K_DIM;
    const int ldst = t * 8;                        // u16 offset inside region

#define STAGE_A(S, K0) do { u16* d_ = lds + (S) * SLOT_U16 + ldst;            \
        gload16(gA0 + (K0), d_); gload16(gA1 + (K0), d_ + 4096); } while (0)
#define STAGE_B(S, K0) do { u16* d_ = lds + (S) * SLOT_U16 + 8192 + ldst;     \
        gload16(gB0 + (K0), d_); gload16(gB1 + (K0), d_ + 4096); } while (0)

    // fragment read offsets: lane-contiguous 1KB per fragment -> conflict-free
    const int aoff = (wrow * 8) * 512 + quad * 128 + l15 * 8;
    const int boff = (wcol * 4) * 512 + quad * 128 + l15 * 8;

    f32x4 acc[8][4];
#pragma unroll
    for (int i = 0; i < 8; ++i)
#pragma unroll
        for (int j = 0; j < 4; ++j) acc[i][j] = (f32x4){0.f, 0.f, 0.f, 0.f};

    // prologue: stage tiles 0,1,2 (12 loads/thread); wait oldest 4 (tile 0)
    STAGE_A(0, 0);      STAGE_B(0, 0);
    STAGE_A(1, BK);     STAGE_B(1, BK);
    STAGE_A(2, 2 * BK); STAGE_B(2, 2 * BK);
    asm volatile("s_waitcnt vmcnt(8)" ::: "memory");
    __builtin_amdgcn_s_barrier();

    for (int tt = 0; tt < NT; ++tt) {
        const u16* As = lds + (tt & 3) * SLOT_U16;
        const u16* Bs = As + 8192;
        const bool doStage = (tt + 3) < NT;
        const int ss = (tt + 3) & 3;              // == (tt-1)&3 : safe slot
        const int sk = (tt + 3) * BK;

        // ---- issue everything up front: 12 ds_read_b128 + 4 gload_lds ----
        bf16x8 af[8], bf[4];
#pragma unroll
        for (int i = 0; i < 4; ++i) af[i] = *(const bf16x8*)(As + aoff + i * 512);
#pragma unroll
        for (int i = 0; i < 4; ++i) bf[i] = *(const bf16x8*)(Bs + boff + i * 512);
        if (doStage) STAGE_A(ss, sk);
#pragma unroll
        for (int i = 4; i < 8; ++i) af[i] = *(const bf16x8*)(As + aoff + i * 512);
        if (doStage) STAGE_B(ss, sk);

        // ---- 32 MFMAs; compiler emits counted lgkmcnt so the first ones
        //      start while the tail ds_reads are still in flight ----
        __builtin_amdgcn_s_setprio(1);
#pragma unroll
        for (int mi = 0; mi < 8; ++mi)
#pragma unroll
            for (int ni = 0; ni < 4; ++ni)
                acc[mi][ni] = __builtin_amdgcn_mfma_f32_16x16x32_bf16(
                    af[mi], bf[ni], acc[mi][ni], 0, 0, 0);
        __builtin_amdgcn_s_setprio(0);

        // tile boundary: counted wait readies tile tt+1 (all waves wait
        // BEFORE the barrier -> cross-wave staging visible after it)
        if (tt < NT - 3)       asm volatile("s_waitcnt vmcnt(8)" ::: "memory");
        else if (tt == NT - 3) asm volatile("s_waitcnt vmcnt(4)" ::: "memory");
        else if (tt == NT - 2) asm volatile("s_waitcnt vmcnt(0)" ::: "memory");
        __builtin_amdgcn_s_barrier();
    }

    // epilogue: C/D layout col = lane&15, row = quad*4 + r  [m89-verified]
#pragma unroll
    for (int mi = 0; mi < 8; ++mi) {
        const int row0 = bm + wrow * 128 + mi * 16 + quad * 4;
#pragma unroll
        for (int ni = 0; ni < 4; ++ni) {
            const int col = bn + wcol * 64 + ni * 16 + l15;
#pragma unroll
            for (int r = 0; r < 4; ++r)
                C[(size_t)(row0 + r) * N_DIM + col] = acc[mi][ni][r];
        }
    }
#undef STAGE_A
#undef STAGE_B
}

extern "C" void kernel_launch(void* const* d_in, const int* in_sizes, int n_in,
                              void* d_out, int out_size, void* d_ws, size_t ws_size,
                              hipStream_t stream) {
    const float* x  = (const float*)d_in[0];   // [16384][4096]
    const float* wp = (const float*)d_in[1];   // [4096][4096]
    const float* wn = (const float*)d_in[2];
    float* out = (float*)d_out;                // [16384][4096]

    // workspace layout: [0, 128MB) x_bf16 ; [128MB, 160MB) w_bf16
    u16* xb = (u16*)d_ws;
    u16* wb = (u16*)((char*)d_ws + (size_t)M_DIM * K_DIM * sizeof(u16));

    const int nx4 = M_DIM * K_DIM / 4;   // 16,777,216 float4s
    cvt_x_kernel<<<nx4 / 256, 256, 0, stream>>>((const float4*)x, (uint2*)xb, nx4);

    const int nw4 = N_DIM * K_DIM / 4;   // 4,194,304 float4s
    binarize_w_kernel<<<nw4 / 256, 256, 0, stream>>>(
        (const float4*)wp, (const float4*)wn, (uint2*)wb, nw4);

    static int s_attr_done = 0;
    if (!s_attr_done) {
        hipFuncSetAttribute((const void*)gemm_bin_kernel,
                            hipFuncAttributeMaxDynamicSharedMemorySize, LDS_BYTES);
        s_attr_done = 1;
    }
    dim3 grid(N_DIM / BN, M_DIM / BM);   // (16, 64) -> 1024 blocks
    gemm_bin_kernel<<<grid, 512, LDS_BYTES, stream>>>(xb, wb, out);
}